// Round 1
// baseline (15215.453 us; speedup 1.0000x reference)
//
#include <hip/hip_runtime.h>
#include <cmath>

// VanillaRNN: T=1024 steps of h = tanh(U[:,x] + W@h + bh); y = V@h + by.
// Round 0: correctness-first multi-launch baseline.
//   - 1 fused kernel per step: blocks 0..127  -> h-GEMM (W@h, 32x32 tile)
//                              blocks 128..191 -> y-GEMM for PREVIOUS step's h
//   - final kernel: y for t=T-1 + copy hT to output tail.
// d_ws usage: 2 * H*B floats (double-buffered h) = 1 MiB.

namespace {
constexpr int T_ = 1024;
constexpr int B_ = 256;
constexpr int D_ = 256;
constexpr int H_ = 512;
constexpr int O_ = 256;

constexpr int TM = 32;   // tile rows
constexpr int TN = 32;   // tile cols
constexpr int KC = 32;   // k chunk
}  // namespace

__global__ __launch_bounds__(256) void rnn_step(
    const int* __restrict__ xs,      // token ids for this step (B) — h-part only
    const float* __restrict__ hin,   // h_{t} input (H,B); null => final launch (copy mode for h-blocks)
    float* __restrict__ hout,        // h_{t+1} output (H,B)
    const float* __restrict__ yh,    // h used by y-part (H,B)
    float* __restrict__ y_out,       // logits slab for one t: (B,O); null on step 0
    float* __restrict__ hT_out,      // final-h output (H,B); only final launch
    const float* __restrict__ U, const float* __restrict__ W,
    const float* __restrict__ V, const float* __restrict__ bh,
    const float* __restrict__ by) {
  // +2 pad: keeps float2 (8B) alignment of [kk][2*t] reads and <=2-way bank
  // aliasing on writes (2-way is free on gfx950 per measured m136).
  __shared__ float As[KC][TM + 2];
  __shared__ float Xs[KC][TN + 2];

  const int tid = threadIdx.x;
  const int blk = blockIdx.x;
  const bool is_h = (blk < 128);

  if (is_h && hin == nullptr) {
    // Final launch: h-blocks repurposed to copy hT (H*B = 131072 floats).
    const int base = blk * 1024 + tid * 4;
    const float4 v = *(const float4*)&yh[base];
    *(float4*)&hT_out[base] = v;
    return;
  }

  const float* A;
  const float* X;
  int i0, j0;
  if (is_h) {
    A = W;
    X = hin;
    i0 = (blk >> 3) * TM;        // 16 row tiles * 8 col tiles
    j0 = (blk & 7) * TN;
  } else {
    const int b2 = blk - 128;    // 8 x 8 tiles over (O,B)
    A = V;
    X = yh;
    i0 = (b2 >> 3) * TM;
    j0 = (b2 & 7) * TN;
  }

  const int tx = tid & 15;
  const int ty = tid >> 4;

  float a00 = 0.f, a01 = 0.f, a10 = 0.f, a11 = 0.f;

  for (int kc = 0; kc < H_; kc += KC) {
    // Stage A tile transposed: As[kk][r] = A[i0+r][kc+kk]; coalesced global
    // reads (kk contiguous with tid).
#pragma unroll
    for (int n = 0; n < 4; ++n) {
      const int e = tid + n * 256;
      const int kk = e & (KC - 1);
      const int r = e >> 5;
      As[kk][r] = A[(size_t)(i0 + r) * H_ + (kc + kk)];
    }
    // Stage X tile: Xs[kk][c] = X[kc+kk][j0+c]; coalesced (c contiguous).
#pragma unroll
    for (int n = 0; n < 4; ++n) {
      const int e = tid + n * 256;
      const int c = e & (TN - 1);
      const int kk = e >> 5;
      Xs[kk][c] = X[(size_t)(kc + kk) * B_ + (j0 + c)];
    }
    __syncthreads();

#pragma unroll
    for (int kk = 0; kk < KC; ++kk) {
      const float2 wv = *(const float2*)&As[kk][2 * ty];
      const float2 hv = *(const float2*)&Xs[kk][2 * tx];
      a00 += wv.x * hv.x;
      a01 += wv.x * hv.y;
      a10 += wv.y * hv.x;
      a11 += wv.y * hv.y;
    }
    __syncthreads();
  }

  const int i = i0 + 2 * ty;
  const int j = j0 + 2 * tx;

  if (is_h) {
    const int x0 = xs[j];
    const int x1 = xs[j + 1];
    const float bh0 = bh[i];
    const float bh1 = bh[i + 1];
    hout[(size_t)i * B_ + j]           = tanhf(a00 + U[(size_t)i * D_ + x0] + bh0);
    hout[(size_t)i * B_ + j + 1]       = tanhf(a01 + U[(size_t)i * D_ + x1] + bh0);
    hout[(size_t)(i + 1) * B_ + j]     = tanhf(a10 + U[(size_t)(i + 1) * D_ + x0] + bh1);
    hout[(size_t)(i + 1) * B_ + j + 1] = tanhf(a11 + U[(size_t)(i + 1) * D_ + x1] + bh1);
  } else {
    // out layout per t: (B, O): y_out[b*O + o]; o=i contiguous pairs -> float2.
    const float b0 = by[i];
    const float b1 = by[i + 1];
    const float2 c0 = make_float2(a00 + b0, a10 + b1);
    const float2 c1 = make_float2(a01 + b0, a11 + b1);
    *(float2*)&y_out[(size_t)j * O_ + i]       = c0;
    *(float2*)&y_out[(size_t)(j + 1) * O_ + i] = c1;
  }
}

extern "C" void kernel_launch(void* const* d_in, const int* in_sizes, int n_in,
                              void* d_out, int out_size, void* d_ws, size_t ws_size,
                              hipStream_t stream) {
  (void)in_sizes; (void)n_in; (void)out_size; (void)ws_size;
  const int* inputs = (const int*)d_in[0];
  const float* h0 = (const float*)d_in[1];
  const float* U  = (const float*)d_in[2];
  const float* W  = (const float*)d_in[3];
  const float* V  = (const float*)d_in[4];
  const float* bh = (const float*)d_in[5];
  const float* by = (const float*)d_in[6];
  float* out = (float*)d_out;

  float* hb0 = (float*)d_ws;                 // H*B floats
  float* hb1 = hb0 + (size_t)H_ * B_;        // H*B floats

  // Step 0: h only (h0 -> hb0). No y yet.
  rnn_step<<<128, 256, 0, stream>>>(inputs, h0, hb0, nullptr, nullptr, nullptr,
                                    U, W, V, bh, by);

  // Steps 1..T-1: compute h_{s+1}; y for t = s-1 from the stable hin buffer.
  for (int s = 1; s < T_; ++s) {
    const float* hi = (s & 1) ? hb0 : hb1;
    float* ho = (s & 1) ? hb1 : hb0;
    rnn_step<<<192, 256, 0, stream>>>(inputs + (size_t)s * B_, hi, ho, hi,
                                      out + (size_t)(s - 1) * B_ * O_, nullptr,
                                      U, W, V, bh, by);
  }

  // Final: y for t = T-1 (from hb1, written by step 1023) + hT copy.
  rnn_step<<<192, 256, 0, stream>>>(nullptr, nullptr, hb0, hb1,
                                    out + (size_t)(T_ - 1) * B_ * O_,
                                    out + (size_t)T_ * B_ * O_,
                                    U, W, V, bh, by);
}

// Round 3
// 7546.262 us; speedup vs baseline: 2.0163x; 2.0163x over previous
//
#include <hip/hip_runtime.h>
#include <cmath>

// VanillaRNN persistent kernel (R1, compile fix R2).
// h_{t+1} = tanh(U[:,x_t] + W h_t + bh);  y_t = V h_{t+1} + by.
// 256 WGs = 16 row-blocks (32 rows of H) x 16 col-groups (16 cols of B).
// W,V held in registers as split-bf16 MFMA fragments (loaded once).
// Per-step sync: 16 producers per col-group, agent-scope release/acquire flags.
// d_ws: hbuf double buffer (2*H*B f32 = 1 MiB) + flags (16*1025 ints).

typedef __attribute__((ext_vector_type(8))) short short8;
typedef __attribute__((ext_vector_type(4))) float f32x4;

namespace {
constexpr int T_ = 1024, B_ = 256, D_ = 256, H_ = 512, O_ = 256;
constexpr int NRB = 16;          // row blocks (producers per col-group barrier)
constexpr int HB = H_ * B_;      // 131072 floats
constexpr int HSP = 520;         // padded k-stride (shorts) for staged h
}

__device__ __forceinline__ short bf16_rne(float x) {
  unsigned u = __float_as_uint(x);
  unsigned r = u + 0x7FFFu + ((u >> 16) & 1u);
  return (short)(r >> 16);
}
__device__ __forceinline__ float bf16_to_f(short h) {
  return __uint_as_float(((unsigned)(unsigned short)h) << 16);
}

__global__ void rnn_init(const float* __restrict__ h0, float* __restrict__ hbuf,
                         int* __restrict__ flags) {
  const int idx = blockIdx.x * 256 + threadIdx.x;  // grid 128*256 = 32768
  ((f32x4*)hbuf)[idx] = ((const f32x4*)h0)[idx];   // h0 -> buf0 (131072 f32)
  if (idx < 16 * (T_ + 1)) flags[idx] = 0;
}

__global__ __launch_bounds__(256, 1) void rnn_persist(
    const int* __restrict__ xs, const float* __restrict__ U,
    const float* __restrict__ W, const float* __restrict__ V,
    const float* __restrict__ bh, const float* __restrict__ by,
    float* __restrict__ out, float* __restrict__ hbuf, int* __restrict__ flags) {
  const int tid = threadIdx.x;
  const int wg = blockIdx.x;        // 0..255
  const int c = wg & 15;            // col group
  const int r = wg >> 4;            // row block
  const int Ri = r * 32;
  const int Cb = c * 16;
  const int wid = tid >> 6;         // wave 0..3
  const int l = tid & 63;
  const int lm = l & 15;            // MFMA m/n lane index
  const int lq = l >> 4;            // MFMA quad

  const int mh = wid & 1;           // h-GEMM row-half (rows 16*mh..+16)
  const int kh = wid >> 1;          // h-GEMM K-half (256 each)

  __shared__ short hs_hi[16][HSP];  // staged h_t, transposed [col][k], bf16 hi
  __shared__ short hs_lo[16][HSP];  // bf16 residual
  __shared__ float redh[2][16][17];
  __shared__ float redy[3][16][17];
  __shared__ float ytile[16][20];

  // ---- Preload weight fragments (registers, once) ----
  // A-frag layout (verified m89/m91/m120): A[m=lane&15][k=quad*8+j].
  short8 whi[8], wlo[8];
  {
    const float* p0 = W + (size_t)(Ri + 16 * mh + lm) * H_ + kh * 256 + lq * 8;
#pragma unroll
    for (int kk = 0; kk < 8; ++kk) {
      const float* p = p0 + kk * 32;
      short8 a, b;
#pragma unroll
      for (int j = 0; j < 8; ++j) {
        float x = p[j];
        short hi = bf16_rne(x);
        a[j] = hi;
        b[j] = bf16_rne(x - bf16_to_f(hi));
      }
      whi[kk] = a; wlo[kk] = b;
    }
  }
  short8 vhi[4], vlo[4];
  {
    const float* p0 = V + (size_t)(16 * r + lm) * H_ + wid * 128 + lq * 8;
#pragma unroll
    for (int kk = 0; kk < 4; ++kk) {
      const float* p = p0 + kk * 32;
      short8 a, b;
#pragma unroll
      for (int j = 0; j < 8; ++j) {
        float x = p[j];
        short hi = bf16_rne(x);
        a[j] = hi;
        b[j] = bf16_rne(x - bf16_to_f(hi));
      }
      vhi[kk] = a; vlo[kk] = b;
    }
  }
  float bhv[4], byv[4];
#pragma unroll
  for (int p = 0; p < 4; ++p) {
    bhv[p] = bh[Ri + 16 * mh + lq * 4 + p];   // used by waves 0,1 (kh==0)
    byv[p] = by[16 * r + lq * 4 + p];         // used by wave 2
  }

  for (int t = 0; t <= T_; ++t) {
    // ---- 1. wait for h_t complete (16 producers) ----
    if (t > 0) {
      if (tid == 0) {
        int* f = &flags[c * (T_ + 1) + t];
        while (__hip_atomic_load(f, __ATOMIC_RELAXED, __HIP_MEMORY_SCOPE_AGENT) < NRB)
          __builtin_amdgcn_s_sleep(1);
        (void)__hip_atomic_load(f, __ATOMIC_ACQUIRE, __HIP_MEMORY_SCOPE_AGENT);
      }
      __syncthreads();
    }
    const float* hsrc = hbuf + (size_t)(t & 1) * HB;

    // ---- 2. early t-dependent loads (latency hidden behind staging/MFMA) ----
    float uv[4];
    if (wid < 2 && t < T_) {
      const int xv = xs[(size_t)t * B_ + Cb + lm];
#pragma unroll
      for (int p = 0; p < 4; ++p)
        uv[p] = U[(size_t)(Ri + 16 * mh + lq * 4 + p) * D_ + xv];
    }

    // ---- 3. stage h_t -> LDS transposed split-bf16 ----
    {
      const int scol = tid & 15;
      const int sk0 = (tid >> 4) * 32;
      const float* hp = hsrc + Cb + scol;
      float hv[32];
#pragma unroll
      for (int i = 0; i < 32; ++i) hv[i] = hp[(size_t)(sk0 + i) * B_];
      short hhi[32], hlo[32];
#pragma unroll
      for (int i = 0; i < 32; ++i) {
        short hi = bf16_rne(hv[i]);
        hhi[i] = hi;
        hlo[i] = bf16_rne(hv[i] - bf16_to_f(hi));
      }
#pragma unroll
      for (int g = 0; g < 4; ++g) {
        short8 a, b;
#pragma unroll
        for (int j = 0; j < 8; ++j) { a[j] = hhi[8 * g + j]; b[j] = hlo[8 * g + j]; }
        *(short8*)&hs_hi[scol][sk0 + 8 * g] = a;
        *(short8*)&hs_lo[scol][sk0 + 8 * g] = b;
      }
    }
    __syncthreads();

    // ---- 4. partial MFMAs (split-bf16 3-pass) ----
    f32x4 acc_h = {0.f, 0.f, 0.f, 0.f};
    if (t < T_) {
#pragma unroll
      for (int kk = 0; kk < 8; ++kk) {
        const int k0 = kh * 256 + kk * 32 + lq * 8;
        short8 bhi8 = *(const short8*)&hs_hi[lm][k0];
        short8 blo8 = *(const short8*)&hs_lo[lm][k0];
        acc_h = __builtin_amdgcn_mfma_f32_16x16x32_bf16(whi[kk], bhi8, acc_h, 0, 0, 0);
        acc_h = __builtin_amdgcn_mfma_f32_16x16x32_bf16(wlo[kk], bhi8, acc_h, 0, 0, 0);
        acc_h = __builtin_amdgcn_mfma_f32_16x16x32_bf16(whi[kk], blo8, acc_h, 0, 0, 0);
      }
    }
    f32x4 acc_y = {0.f, 0.f, 0.f, 0.f};
    if (t >= 1) {
#pragma unroll
      for (int kk = 0; kk < 4; ++kk) {
        const int k0 = wid * 128 + kk * 32 + lq * 8;
        short8 bhi8 = *(const short8*)&hs_hi[lm][k0];
        short8 blo8 = *(const short8*)&hs_lo[lm][k0];
        acc_y = __builtin_amdgcn_mfma_f32_16x16x32_bf16(vhi[kk], bhi8, acc_y, 0, 0, 0);
        acc_y = __builtin_amdgcn_mfma_f32_16x16x32_bf16(vlo[kk], bhi8, acc_y, 0, 0, 0);
        acc_y = __builtin_amdgcn_mfma_f32_16x16x32_bf16(vhi[kk], blo8, acc_y, 0, 0, 0);
      }
    }

    // ---- 5. cross-wave K reductions via LDS ----
    if (t < T_ && kh == 1) {
#pragma unroll
      for (int p = 0; p < 4; ++p) redh[mh][lq * 4 + p][lm] = acc_h[p];
    }
    if (t >= 1 && wid != 2) {
      const int slot = (wid < 2) ? wid : 2;  // waves 0,1,3 -> 0,1,2
#pragma unroll
      for (int p = 0; p < 4; ++p) redy[slot][lq * 4 + p][lm] = acc_y[p];
    }
    __syncthreads();

    // ---- 6. finalize ----
    if (t < T_ && kh == 0) {  // waves 0,1: h_{t+1}
      float* hdst = hbuf + (size_t)((t + 1) & 1) * HB;
#pragma unroll
      for (int p = 0; p < 4; ++p) {
        const int row = lq * 4 + p;
        float pre = acc_h[p] + redh[mh][row][lm] + uv[p] + bhv[p];
        float hvv = tanhf(pre);
        const int i = Ri + 16 * mh + row;
        // write-through agent store: no dirty L2 lines to lose/flush
        __hip_atomic_store(&hdst[(size_t)i * B_ + Cb + lm], hvv,
                           __ATOMIC_RELAXED, __HIP_MEMORY_SCOPE_AGENT);
        if (t == T_ - 1)
          __builtin_nontemporal_store(
              hvv, &out[(size_t)T_ * B_ * O_ + (size_t)i * B_ + Cb + lm]);
      }
    }
    if (t >= 1 && wid == 2) {  // wave 2: y_{t-1}
#pragma unroll
      for (int p = 0; p < 4; ++p) {
        const int row = lq * 4 + p;
        float yv = acc_y[p] + redy[0][row][lm] + redy[1][row][lm] +
                   redy[2][row][lm] + byv[p];
        ytile[lm][row] = yv;  // transposed write [b][o]
      }
      // intra-wave LDS transpose read
      const int bb = l >> 2, oj = l & 3;
      f32x4 yo = *(const f32x4*)&ytile[bb][oj * 4];
      __builtin_nontemporal_store(
          yo, (f32x4*)&out[(size_t)(t - 1) * B_ * O_ + (size_t)(Cb + bb) * O_ +
                           16 * r + oj * 4]);
    }
    __syncthreads();  // drains stores + protects hs reuse

    // ---- 7. publish h_{t+1} ----
    if (t < T_ && tid == 0)
      __hip_atomic_fetch_add(&flags[c * (T_ + 1) + t + 1], 1, __ATOMIC_RELEASE,
                             __HIP_MEMORY_SCOPE_AGENT);
  }
}

extern "C" void kernel_launch(void* const* d_in, const int* in_sizes, int n_in,
                              void* d_out, int out_size, void* d_ws, size_t ws_size,
                              hipStream_t stream) {
  (void)in_sizes; (void)n_in; (void)out_size; (void)ws_size;
  const int* xs = (const int*)d_in[0];
  const float* h0 = (const float*)d_in[1];
  const float* U  = (const float*)d_in[2];
  const float* W  = (const float*)d_in[3];
  const float* V  = (const float*)d_in[4];
  const float* bh = (const float*)d_in[5];
  const float* by = (const float*)d_in[6];
  float* out = (float*)d_out;

  float* hbuf = (float*)d_ws;                       // 2*HB floats = 1 MiB
  int* flags = (int*)((char*)d_ws + (size_t)2 * HB * 4);  // 16*1025 ints

  rnn_init<<<128, 256, 0, stream>>>(h0, hbuf, flags);

  void* args[] = {(void*)&xs, (void*)&U, (void*)&W, (void*)&V, (void*)&bh,
                  (void*)&by, (void*)&out, (void*)&hbuf, (void*)&flags};
  (void)hipLaunchCooperativeKernel((void*)rnn_persist, dim3(256), dim3(256),
                                   args, 0, stream);
}